// Round 4
// baseline (337.188 us; speedup 1.0000x reference)
//
#include <hip/hip_runtime.h>

typedef unsigned short u16;
typedef unsigned int u32;

#define E_EDGES 600000
#define NUM_FINE 50000
#define NUM_COARSE 12500
#define FINE_BLOCKS 391     // ceil(50000/128)
#define COARSE_BLOCKS 98    // ceil(12500/128)
#define CONVERT_BLOCKS 320
#define COUNT_BLOCKS 2344   // ceil(600000/256)
#define ZOUT_BLOCKS 625     // 625*256*4*10 = 6.4e6 floats = out
#define SCATTER_BLOCKS 2344

typedef __attribute__((ext_vector_type(8))) short short8;
typedef __attribute__((ext_vector_type(4))) float f32x4;

union Frag { short8 v; u16 s[8]; u32 u[4]; uint4 q; };

__device__ __forceinline__ u32 rne_bf16(float f) {
  union { float f; u32 u; } v; v.f = f;
  return (v.u + 0x7FFFu + ((v.u >> 16) & 1u)) >> 16;
}
// bf16-pair unpack: 1 VALU op each
__device__ __forceinline__ float hi_bf(u32 u) {
  union { u32 x; float f; } v; v.x = u & 0xFFFF0000u; return v.f;
}
__device__ __forceinline__ float lo_bf(u32 u) {
  union { u32 x; float f; } v; v.x = u << 16; return v.f;
}
// truncating bf16-pair pack: single v_perm_b32
__device__ __forceinline__ u32 pack_trunc(float hi, float lo) {
  union { float f; u32 x; } a, b; a.f = hi; b.f = lo;
  return __builtin_amdgcn_perm(a.x, b.x, 0x07060302u);
}
__device__ __forceinline__ u32 addrelu_pack(u32 a, u32 b) {
  float lo = fmaxf(lo_bf(a) + lo_bf(b), 0.0f);
  float hi = fmaxf(hi_bf(a) + hi_bf(b), 0.0f);
  return pack_trunc(hi, lo);
}
__device__ __forceinline__ u16 trunc_bf16(float f) {
  union { float f; u32 u; } v; v.f = f;
  return (u16)(v.u >> 16);
}

// ---------------------------------------------------------------------------
// prep1: [0,320) convert W1/W2 to fragment-ordered bf16 (RNE);
//        [320,320+2344) count fidx; [.., +625) zero-fill out.
// Fragment layout: [ks][nt][lane][j], value = W[k=ks*32+(lane>>4)*8+j][n=nt*16+(lane&15)]
// ---------------------------------------------------------------------------
__global__ void prep1(const float* __restrict__ W1, const float* __restrict__ W2,
                      u16* __restrict__ BW1f, u16* __restrict__ BW1c,
                      u16* __restrict__ BW2,
                      const int* __restrict__ fidx, int* __restrict__ cnt,
                      float* __restrict__ out) {
  if (blockIdx.x < CONVERT_BLOCKS) {
    int o = blockIdx.x * 256 + threadIdx.x;
    if (o >= 81920) return;
    int which = (o < 32768) ? 0 : (o < 65536 ? 1 : 2);
    int idx = (which == 2) ? (o - 65536) : (o & 32767);
    int j = idx & 7, lane = (idx >> 3) & 63, nt = (idx >> 9) & 7, ks = idx >> 12;
    int k = ks * 32 + (lane >> 4) * 8 + j;
    int n = nt * 16 + (lane & 15);
    float v;
    if (which == 2) v = W2[k * 128 + n];
    else {
      int row;
      if (which == 0) row = (k < 128) ? k : (256 + (k - 128));          // si | di
      else            row = (k < 128) ? (128 + k) : (384 + (k - 128));  // sk | dk
      v = W1[row * 128 + n];
    }
    u16 b = (u16)rne_bf16(v);
    if (which == 0) BW1f[idx] = b; else if (which == 1) BW1c[idx] = b; else BW2[idx] = b;
  } else if (blockIdx.x < CONVERT_BLOCKS + COUNT_BLOCKS) {
    int e = (blockIdx.x - CONVERT_BLOCKS) * 256 + threadIdx.x;
    if (e < E_EDGES) atomicAdd(&cnt[fidx[e]], 1);
  } else {
    const int zb = blockIdx.x - (CONVERT_BLOCKS + COUNT_BLOCKS);
    float4* o4 = (float4*)out;
    const float4 z = {0.f, 0.f, 0.f, 0.f};
    int idx = zb * 2560 + threadIdx.x;
#pragma unroll
    for (int i = 0; i < 10; ++i) o4[idx + i * 256] = z;
  }
}

// ---------------------------------------------------------------------------
// scan: exclusive prefix over cnt[50000] -> wcur. One block, 1024 threads,
// 49 contiguous elements/thread, single pass (2 L1-hot sweeps).
// ---------------------------------------------------------------------------
#define SCAN_PER 49  // 1024*49 >= 50000
__global__ void scan_kernel(const int* __restrict__ cnt, int* __restrict__ wcur) {
  __shared__ int wsum[16], woff[16];
  const int tid = threadIdx.x, lane = tid & 63, w = tid >> 6;
  const int base = tid * SCAN_PER;
  const int n = (base < NUM_FINE) ? min(SCAN_PER, NUM_FINE - base) : 0;
  int s = 0;
  for (int i = 0; i < n; ++i) s += cnt[base + i];
  int x = s;
#pragma unroll
  for (int off = 1; off < 64; off <<= 1) {
    int y = __shfl_up(x, off, 64);
    if (lane >= off) x += y;
  }
  if (lane == 63) wsum[w] = x;
  __syncthreads();
  if (tid == 0) {
    int a = 0;
    for (int k = 0; k < 16; ++k) { int t = wsum[k]; woff[k] = a; a += t; }
  }
  __syncthreads();
  int run = woff[w] + x - s;  // thread's exclusive prefix
  for (int i = 0; i < n; ++i) { wcur[base + i] = run; run += cnt[base + i]; }
}

// ---------------------------------------------------------------------------
// prep2: [0,2344) scatter sorted edge packs; [2344,2344+489) precompute P.
// ---------------------------------------------------------------------------
__global__ __launch_bounds__(256, 2) void prep2(
    const int* __restrict__ fidx, const int* __restrict__ cidx,
    int* __restrict__ wcur, u32* __restrict__ spk,
    const float* __restrict__ h_dk, const float* __restrict__ h_si,
    const float* __restrict__ h_sk, const float* __restrict__ h_di,
    const u16* __restrict__ BW1f, const u16* __restrict__ BW1c,
    const float* __restrict__ b1, u16* __restrict__ Pf, u16* __restrict__ Pc) {
  __shared__ u16 bsh[32768];  // 64 KB (W1-slice fragments)

  if (blockIdx.x < SCATTER_BLOCKS) {
    int e = blockIdx.x * 256 + threadIdx.x;
    if (e < E_EDGES) {
      int fi = fidx[e];
      int p = atomicAdd(&wcur[fi], 1);
      spk[p] = ((u32)fi << 14) | (u32)cidx[e];  // fi<2^16, ci<2^14
    }
    return;
  }

  const int b = blockIdx.x - SCATTER_BLOCKS;
  const bool fine = b < FINE_BLOCKS;
  const int rowStart = fine ? b * 128 : (b - FINE_BLOCKS) * 128;
  const int R = fine ? NUM_FINE : NUM_COARSE;
  const float* __restrict__ X1 = fine ? h_si : h_sk;
  const float* __restrict__ X2 = fine ? h_di : h_dk;
  const u16* __restrict__ BW = fine ? BW1f : BW1c;
  u16* __restrict__ P = fine ? Pf : Pc;

  const int tid = threadIdx.x;
  {  // stage 64 KB of B fragments, coalesced
    uint4* d4 = (uint4*)bsh;
    const uint4* s4 = (const uint4*)BW;
#pragma unroll
    for (int k = 0; k < 16; ++k) d4[k * 256 + tid] = s4[k * 256 + tid];
  }
  __syncthreads();

  const int lane = tid & 63;
  const int w = tid >> 6;
  const int qd = lane >> 4;
  const int ml = lane & 15;

  int rowA[2]; bool vA[2];
#pragma unroll
  for (int mt = 0; mt < 2; ++mt) {
    rowA[mt] = rowStart + w * 32 + mt * 16 + ml;
    vA[mt] = rowA[mt] < R;
  }

  f32x4 acc[2][8];
#pragma unroll
  for (int mt = 0; mt < 2; ++mt)
#pragma unroll
    for (int nt = 0; nt < 8; ++nt) acc[mt][nt] = (f32x4){0.f, 0.f, 0.f, 0.f};

  for (int ks = 0; ks < 8; ++ks) {
    const int k0 = ks * 32 + qd * 8;  // 0..255
    short8 a[2];
#pragma unroll
    for (int mt = 0; mt < 2; ++mt) {
      Frag af;
      if (vA[mt]) {
        const float* src = (k0 < 128) ? (X1 + rowA[mt] * 128 + k0)
                                      : (X2 + rowA[mt] * 128 + (k0 - 128));
        const float4* s4 = (const float4*)src;
        float4 v0 = s4[0], v1 = s4[1];
        af.u[0] = pack_trunc(v0.y, v0.x);
        af.u[1] = pack_trunc(v0.w, v0.z);
        af.u[2] = pack_trunc(v1.y, v1.x);
        af.u[3] = pack_trunc(v1.w, v1.z);
      } else {
        af.u[0] = af.u[1] = af.u[2] = af.u[3] = 0u;
      }
      a[mt] = af.v;
    }
#pragma unroll
    for (int nt = 0; nt < 8; ++nt) {
      Frag bfr;
      bfr.q = *(const uint4*)&bsh[(((ks * 8 + nt) * 64) + lane) * 8];
      acc[0][nt] = __builtin_amdgcn_mfma_f32_16x16x32_bf16(a[0], bfr.v, acc[0][nt], 0, 0, 0);
      acc[1][nt] = __builtin_amdgcn_mfma_f32_16x16x32_bf16(a[1], bfr.v, acc[1][nt], 0, 0, 0);
    }
  }

  float b1v[8];
#pragma unroll
  for (int nt = 0; nt < 8; ++nt) b1v[nt] = fine ? 0.0f : b1[nt * 16 + ml];

#pragma unroll
  for (int mt = 0; mt < 2; ++mt) {
#pragma unroll
    for (int r = 0; r < 4; ++r) {
      const int row = rowStart + w * 32 + mt * 16 + qd * 4 + r;
      if (row < R) {
#pragma unroll
        for (int nt = 0; nt < 8; ++nt)
          P[row * 128 + nt * 16 + ml] = (u16)rne_bf16(acc[mt][nt][r] + b1v[nt]);
      }
    }
  }
}

// ---------------------------------------------------------------------------
// edge_kernel: 128 SORTED edges/block. W2 staged in LDS (32 KB), K-loop MFMA,
// same 32 KB reused as [128][128] bf16 contribution matrix; segment-sum via
// plain ds_read; global atomics only at block boundaries.
// ---------------------------------------------------------------------------
__global__ __launch_bounds__(256, 4) void edge_kernel(
    const u16* __restrict__ Pf, const u16* __restrict__ Pc,
    const u16* __restrict__ BW2, const float* __restrict__ hdk,
    const u32* __restrict__ spk, const float* __restrict__ b2,
    float* __restrict__ out) {
  __shared__ u16 smem[16384];  // 32 KB: W2 frags, then contrib[128][128] bf16
  __shared__ int sh_fi[128], sh_ci[128], sh_segstart[130];
  __shared__ int shS, shHead, shTail, shW0tot;

  const int tid = threadIdx.x;
  const int eb = blockIdx.x * 128;
  const int V = min(128, E_EDGES - eb);

  {  // stage W2 fragments (32 KB), coalesced
    uint4* d4 = (uint4*)smem;
    const uint4* s4 = (const uint4*)BW2;
#pragma unroll
    for (int k = 0; k < 8; ++k) d4[k * 256 + tid] = s4[k * 256 + tid];
  }
  if (tid < 128) {
    if (tid < V) {
      u32 p = spk[eb + tid];
      sh_fi[tid] = (int)(p >> 14);
      sh_ci[tid] = (int)(p & 16383u);
    } else { sh_fi[tid] = -1; sh_ci[tid] = 0; }
  }
  if (tid == 0) {
    shHead = (eb > 0) ? (int)(spk[eb - 1] >> 14) : -1;
    shTail = (eb + V < E_EDGES) ? (int)(spk[eb + V] >> 14) : -1;
  }
  __syncthreads();

  // segment scan over the 128 rows (waves 0-1)
  int f = 0, x = 0;
  if (tid < 128) {
    f = (tid < V) ? ((tid == 0) ? 1 : (sh_fi[tid] != sh_fi[tid - 1] ? 1 : 0)) : 0;
    x = f;
#pragma unroll
    for (int off = 1; off < 64; off <<= 1) {
      int y = __shfl_up(x, off, 64);
      if ((tid & 63) >= off) x += y;
    }
  }
  if (tid == 63) shW0tot = x;
  __syncthreads();
  if (tid >= 64 && tid < 128) x += shW0tot;
  if (tid < V) {
    if (f) sh_segstart[x - 1] = tid;
    if (tid == V - 1) { shS = x; sh_segstart[x] = V; }
  }
  __syncthreads();

  const int lane = tid & 63;
  const int w = tid >> 6;
  const int qd = lane >> 4;
  const int ml = lane & 15;

  int fiA[2], ciA[2]; bool vA[2];
#pragma unroll
  for (int mt = 0; mt < 2; ++mt) {
    const int lr = w * 32 + mt * 16 + ml;
    vA[mt] = lr < V;
    fiA[mt] = vA[mt] ? sh_fi[lr] : 0;
    ciA[mt] = vA[mt] ? sh_ci[lr] : 0;
  }

  f32x4 acc[2][8];
#pragma unroll
  for (int mt = 0; mt < 2; ++mt)
#pragma unroll
    for (int nt = 0; nt < 8; ++nt) acc[mt][nt] = (f32x4){0.f, 0.f, 0.f, 0.f};

  for (int ks = 0; ks < 4; ++ks) {
    const int k0 = ks * 32 + qd * 8;
    short8 a[2];
#pragma unroll
    for (int mt = 0; mt < 2; ++mt) {
      Frag af;
      if (vA[mt]) {
        uint4 pf = *(const uint4*)(Pf + fiA[mt] * 128 + k0);
        uint4 pc = *(const uint4*)(Pc + ciA[mt] * 128 + k0);
        af.u[0] = addrelu_pack(pf.x, pc.x);
        af.u[1] = addrelu_pack(pf.y, pc.y);
        af.u[2] = addrelu_pack(pf.z, pc.z);
        af.u[3] = addrelu_pack(pf.w, pc.w);
      } else {
        af.u[0] = af.u[1] = af.u[2] = af.u[3] = 0u;
      }
      a[mt] = af.v;
    }
#pragma unroll
    for (int nt = 0; nt < 8; ++nt) {
      Frag bfr;
      bfr.q = *(const uint4*)&smem[(((ks * 8 + nt) * 64) + lane) * 8];
      acc[0][nt] = __builtin_amdgcn_mfma_f32_16x16x32_bf16(a[0], bfr.v, acc[0][nt], 0, 0, 0);
      acc[1][nt] = __builtin_amdgcn_mfma_f32_16x16x32_bf16(a[1], bfr.v, acc[1][nt], 0, 0, 0);
    }
  }
  __syncthreads();  // all W2 LDS reads done; smem is now the contrib matrix

  float b2v[8];
#pragma unroll
  for (int nt = 0; nt < 8; ++nt) b2v[nt] = b2[nt * 16 + ml];

#pragma unroll
  for (int mt = 0; mt < 2; ++mt) {
#pragma unroll
    for (int r = 0; r < 4; ++r) {
      const int lr = w * 32 + mt * 16 + qd * 4 + r;
      if (lr < V) {
        const float* __restrict__ hrow = hdk + sh_ci[lr] * 128;
#pragma unroll
        for (int nt = 0; nt < 8; ++nt) {
          const int col = nt * 16 + ml;
          const float psi = fmaxf(acc[mt][nt][r] + b2v[nt], 0.0f);
          smem[lr * 128 + col] = trunc_bf16(psi * hrow[col]);
        }
      }
    }
  }
  __syncthreads();

  // segment reduce: thread owns (segment, col-pair); plain LDS reads, one
  // store (or boundary atomic) per output element.
  const int S = shS;
  for (int idx = tid; idx < S * 64; idx += 256) {
    const int s = idx >> 6, cp = idx & 63;
    const int r0 = sh_segstart[s], r1 = sh_segstart[s + 1];
    float a0 = 0.f, a1 = 0.f;
    for (int r = r0; r < r1; ++r) {
      const u32 v = *(const u32*)&smem[r * 128 + cp * 2];
      a0 += lo_bf(v);
      a1 += hi_bf(v);
    }
    const int fi = sh_fi[r0];
    float* op = out + (size_t)fi * 128 + cp * 2;
    const bool at = (s == 0 && shHead == fi) || (s == S - 1 && shTail == fi);
    if (at) { atomicAdd(op, a0); atomicAdd(op + 1, a1); }
    else { op[0] = a0; op[1] = a1; }
  }
}

extern "C" void kernel_launch(void* const* d_in, const int* in_sizes, int n_in,
                              void* d_out, int out_size, void* d_ws, size_t ws_size,
                              hipStream_t stream) {
  const float* h_dk = (const float*)d_in[0];
  const float* h_si = (const float*)d_in[1];
  const float* h_sk = (const float*)d_in[2];
  const float* h_di = (const float*)d_in[3];
  const int* fidx = (const int*)d_in[4];
  const int* cidx = (const int*)d_in[5];
  const float* W1 = (const float*)d_in[6];
  const float* b1 = (const float*)d_in[7];
  const float* W2 = (const float*)d_in[8];
  const float* b2 = (const float*)d_in[9];
  float* out = (float*)d_out;

  u16* Pf   = (u16*)d_ws;                      // 50000*128 bf16
  u16* Pc   = Pf + (size_t)NUM_FINE * 128;     // 12500*128 bf16
  u16* BW1f = Pc + (size_t)NUM_COARSE * 128;   // 32768
  u16* BW1c = BW1f + 32768;                    // 32768
  u16* BW2  = BW1c + 32768;                    // 16384
  int* cnt  = (int*)(BW2 + 16384);             // 50000
  int* wcur = cnt + NUM_FINE;                  // 50000
  u32* spk  = (u32*)(wcur + NUM_FINE);         // 600000

  hipMemsetAsync(cnt, 0, NUM_FINE * sizeof(int), stream);

  prep1<<<CONVERT_BLOCKS + COUNT_BLOCKS + ZOUT_BLOCKS, 256, 0, stream>>>(
      W1, W2, BW1f, BW1c, BW2, fidx, cnt, out);
  scan_kernel<<<1, 1024, 0, stream>>>(cnt, wcur);
  prep2<<<SCATTER_BLOCKS + FINE_BLOCKS + COARSE_BLOCKS, 256, 0, stream>>>(
      fidx, cidx, wcur, spk, h_dk, h_si, h_sk, h_di, BW1f, BW1c, b1, Pf, Pc);
  edge_kernel<<<(E_EDGES + 127) / 128, 256, 0, stream>>>(
      Pf, Pc, BW2, h_dk, spk, b2, out);
}

// Round 5
// 332.546 us; speedup vs baseline: 1.0140x; 1.0140x over previous
//
#include <hip/hip_runtime.h>

typedef unsigned char u8;
typedef unsigned short u16;
typedef unsigned int u32;

#define E_EDGES 600000
#define NUM_FINE 50000
#define NUM_COARSE 12500
#define FINE_BLOCKS 391     // ceil(50000/128)
#define COARSE_BLOCKS 98    // ceil(12500/128)
#define CONVERT_BLOCKS 320
#define HCONV_BLOCKS 782    // ceil(1.6M/(256*8))
#define COUNT_BLOCKS 2344   // ceil(600000/256)
#define SCATTER_BLOCKS 2344
#define ZOUT_BLOCKS 625     // 625*256*10 float4 = 6.4M floats
#define PADF 53248          // 1024*52, padded per-copy counter length

typedef __attribute__((ext_vector_type(8))) short short8;
typedef __attribute__((ext_vector_type(4))) float f32x4;

union Frag { short8 v; u16 s[8]; u32 u[4]; uint4 q; };

__device__ __forceinline__ u32 rne_bf16(float f) {
  union { float f; u32 u; } v; v.f = f;
  return (v.u + 0x7FFFu + ((v.u >> 16) & 1u)) >> 16;
}
__device__ __forceinline__ float hi_bf(u32 u) {
  union { u32 x; float f; } v; v.x = u & 0xFFFF0000u; return v.f;
}
__device__ __forceinline__ float lo_bf(u32 u) {
  union { u32 x; float f; } v; v.x = u << 16; return v.f;
}
__device__ __forceinline__ float up_bf(u16 u) {
  union { u32 x; float f; } v; v.x = ((u32)u) << 16; return v.f;
}
__device__ __forceinline__ u32 pack_trunc(float hi, float lo) {
  union { float f; u32 x; } a, b; a.f = hi; b.f = lo;
  return __builtin_amdgcn_perm(a.x, b.x, 0x07060302u);
}
__device__ __forceinline__ u32 addrelu_pack(u32 a, u32 b) {
  float lo = fmaxf(lo_bf(a) + lo_bf(b), 0.0f);
  float hi = fmaxf(hi_bf(a) + hi_bf(b), 0.0f);
  return pack_trunc(hi, lo);
}
__device__ __forceinline__ u16 trunc_bf16(float f) {
  union { float f; u32 u; } v; v.f = f;
  return (u16)(v.u >> 16);
}
__device__ __forceinline__ u32 rne_pack(float lo, float hi) {
  return rne_bf16(lo) | (rne_bf16(hi) << 16);
}

// ---------------------------------------------------------------------------
// prep1: [0,320) convert W1/W2 to fragment-ordered bf16;
//        [320,+782) convert h_dk -> bf16 Hc;
//        [+2344) count fidx into 4 privatized copies, record rank u8.
// ---------------------------------------------------------------------------
__global__ void prep1(const float* __restrict__ W1, const float* __restrict__ W2,
                      u16* __restrict__ BW1f, u16* __restrict__ BW1c,
                      u16* __restrict__ BW2,
                      const float* __restrict__ h_dk, u16* __restrict__ Hc,
                      const int* __restrict__ fidx, u32* __restrict__ cnt4,
                      u8* __restrict__ rk) {
  if (blockIdx.x < CONVERT_BLOCKS) {
    int o = blockIdx.x * 256 + threadIdx.x;
    if (o >= 81920) return;
    int which = (o < 32768) ? 0 : (o < 65536 ? 1 : 2);
    int idx = (which == 2) ? (o - 65536) : (o & 32767);
    int j = idx & 7, lane = (idx >> 3) & 63, nt = (idx >> 9) & 7, ks = idx >> 12;
    int k = ks * 32 + (lane >> 4) * 8 + j;
    int n = nt * 16 + (lane & 15);
    float v;
    if (which == 2) v = W2[k * 128 + n];
    else {
      int row;
      if (which == 0) row = (k < 128) ? k : (256 + (k - 128));          // si | di
      else            row = (k < 128) ? (128 + k) : (384 + (k - 128));  // sk | dk
      v = W1[row * 128 + n];
    }
    u16 b = (u16)rne_bf16(v);
    if (which == 0) BW1f[idx] = b; else if (which == 1) BW1c[idx] = b; else BW2[idx] = b;
  } else if (blockIdx.x < CONVERT_BLOCKS + HCONV_BLOCKS) {
    // convert 8 f32 -> 8 bf16 (uint4 store) per thread
    int t = (blockIdx.x - CONVERT_BLOCKS) * 256 + threadIdx.x;
    if (t < (NUM_COARSE * 128) / 8) {
      const float4* s = (const float4*)(h_dk + t * 8);
      float4 v0 = s[0], v1 = s[1];
      uint4 o;
      o.x = rne_pack(v0.x, v0.y);
      o.y = rne_pack(v0.z, v0.w);
      o.z = rne_pack(v1.x, v1.y);
      o.w = rne_pack(v1.z, v1.w);
      *(uint4*)(Hc + t * 8) = o;
    }
  } else {
    int e = (blockIdx.x - CONVERT_BLOCKS - HCONV_BLOCKS) * 256 + threadIdx.x;
    if (e < E_EDGES) {
      int fi = fidx[e];
      u32 r = atomicAdd(&cnt4[(e & 3) * PADF + fi], 1u);
      rk[e] = (u8)r;
    }
  }
}

// ---------------------------------------------------------------------------
// scan: in-place exclusive bases. cnt4[c][fi] (counts) -> cnt4[c][fi] (bases):
// base[c][fi] = global_excl_scan_fi(tot) + sum_{c'<c} cnt[c'][fi].
// One block, 1024 threads, 52 fi/thread, fully unrolled int4 passes.
// ---------------------------------------------------------------------------
__global__ void scan_kernel(u32* __restrict__ cnt4) {
  __shared__ u32 wsum[16], woff[16];
  const int tid = threadIdx.x, lane = tid & 63, w = tid >> 6;
  const int fi0 = tid * 52;

  u32 tot = 0;
#pragma unroll
  for (int g = 0; g < 13; ++g) {
#pragma unroll
    for (int c = 0; c < 4; ++c) {
      uint4 v = *(const uint4*)(cnt4 + c * PADF + fi0 + g * 4);
      tot += v.x + v.y + v.z + v.w;
    }
  }
  u32 x = tot;
#pragma unroll
  for (int off = 1; off < 64; off <<= 1) {
    u32 y = __shfl_up(x, off, 64);
    if (lane >= off) x += y;
  }
  if (lane == 63) wsum[w] = x;
  __syncthreads();
  if (tid == 0) {
    u32 a = 0;
    for (int k = 0; k < 16; ++k) { u32 t = wsum[k]; woff[k] = a; a += t; }
  }
  __syncthreads();
  u32 run = woff[w] + x - tot;  // thread's global exclusive base

#pragma unroll
  for (int g = 0; g < 13; ++g) {
    uint4 c0 = *(const uint4*)(cnt4 + 0 * PADF + fi0 + g * 4);
    uint4 c1 = *(const uint4*)(cnt4 + 1 * PADF + fi0 + g * 4);
    uint4 c2 = *(const uint4*)(cnt4 + 2 * PADF + fi0 + g * 4);
    uint4 c3 = *(const uint4*)(cnt4 + 3 * PADF + fi0 + g * 4);
    uint4 b0, b1, b2, b3;
    // fi = fi0+g*4+0
    b0.x = run;          b1.x = b0.x + c0.x; b2.x = b1.x + c1.x; b3.x = b2.x + c2.x;
    run = b3.x + c3.x;
    b0.y = run;          b1.y = b0.y + c0.y; b2.y = b1.y + c1.y; b3.y = b2.y + c2.y;
    run = b3.y + c3.y;
    b0.z = run;          b1.z = b0.z + c0.z; b2.z = b1.z + c1.z; b3.z = b2.z + c2.z;
    run = b3.z + c3.z;
    b0.w = run;          b1.w = b0.w + c0.w; b2.w = b1.w + c1.w; b3.w = b2.w + c2.w;
    run = b3.w + c3.w;
    *(uint4*)(cnt4 + 0 * PADF + fi0 + g * 4) = b0;
    *(uint4*)(cnt4 + 1 * PADF + fi0 + g * 4) = b1;
    *(uint4*)(cnt4 + 2 * PADF + fi0 + g * 4) = b2;
    *(uint4*)(cnt4 + 3 * PADF + fi0 + g * 4) = b3;
  }
}

// ---------------------------------------------------------------------------
// prep2: [0,2344) atomic-free scatter; [+625) zero-fill out; [+489) precompute.
// ---------------------------------------------------------------------------
__global__ __launch_bounds__(256, 2) void prep2(
    const int* __restrict__ fidx, const int* __restrict__ cidx,
    const u32* __restrict__ base4, const u8* __restrict__ rk,
    u32* __restrict__ spk, float* __restrict__ out,
    const float* __restrict__ h_dk, const float* __restrict__ h_si,
    const float* __restrict__ h_sk, const float* __restrict__ h_di,
    const u16* __restrict__ BW1f, const u16* __restrict__ BW1c,
    const float* __restrict__ b1, u16* __restrict__ Pf, u16* __restrict__ Pc) {
  __shared__ u16 bsh[32768];  // 64 KB (W1-slice fragments)

  if (blockIdx.x < SCATTER_BLOCKS) {
    int e = blockIdx.x * 256 + threadIdx.x;
    if (e < E_EDGES) {
      int fi = fidx[e];
      u32 pos = base4[(e & 3) * PADF + fi] + rk[e];
      spk[pos] = ((u32)fi << 14) | (u32)cidx[e];  // fi<2^16, ci<2^14
    }
    return;
  }
  if (blockIdx.x < SCATTER_BLOCKS + ZOUT_BLOCKS) {
    const int zb = blockIdx.x - SCATTER_BLOCKS;
    float4* o4 = (float4*)out;
    const float4 z = {0.f, 0.f, 0.f, 0.f};
    int idx = zb * 2560 + threadIdx.x;
#pragma unroll
    for (int i = 0; i < 10; ++i) o4[idx + i * 256] = z;
    return;
  }

  const int b = blockIdx.x - SCATTER_BLOCKS - ZOUT_BLOCKS;
  const bool fine = b < FINE_BLOCKS;
  const int rowStart = fine ? b * 128 : (b - FINE_BLOCKS) * 128;
  const int R = fine ? NUM_FINE : NUM_COARSE;
  const float* __restrict__ X1 = fine ? h_si : h_sk;
  const float* __restrict__ X2 = fine ? h_di : h_dk;
  const u16* __restrict__ BW = fine ? BW1f : BW1c;
  u16* __restrict__ P = fine ? Pf : Pc;

  const int tid = threadIdx.x;
  {  // stage 64 KB of B fragments, coalesced
    uint4* d4 = (uint4*)bsh;
    const uint4* s4 = (const uint4*)BW;
#pragma unroll
    for (int k = 0; k < 16; ++k) d4[k * 256 + tid] = s4[k * 256 + tid];
  }
  __syncthreads();

  const int lane = tid & 63;
  const int w = tid >> 6;
  const int qd = lane >> 4;
  const int ml = lane & 15;

  int rowA[2]; bool vA[2];
#pragma unroll
  for (int mt = 0; mt < 2; ++mt) {
    rowA[mt] = rowStart + w * 32 + mt * 16 + ml;
    vA[mt] = rowA[mt] < R;
  }

  f32x4 acc[2][8];
#pragma unroll
  for (int mt = 0; mt < 2; ++mt)
#pragma unroll
    for (int nt = 0; nt < 8; ++nt) acc[mt][nt] = (f32x4){0.f, 0.f, 0.f, 0.f};

  for (int ks = 0; ks < 8; ++ks) {
    const int k0 = ks * 32 + qd * 8;  // 0..255
    short8 a[2];
#pragma unroll
    for (int mt = 0; mt < 2; ++mt) {
      Frag af;
      if (vA[mt]) {
        const float* src = (k0 < 128) ? (X1 + rowA[mt] * 128 + k0)
                                      : (X2 + rowA[mt] * 128 + (k0 - 128));
        const float4* s4 = (const float4*)src;
        float4 v0 = s4[0], v1 = s4[1];
        af.u[0] = pack_trunc(v0.y, v0.x);
        af.u[1] = pack_trunc(v0.w, v0.z);
        af.u[2] = pack_trunc(v1.y, v1.x);
        af.u[3] = pack_trunc(v1.w, v1.z);
      } else {
        af.u[0] = af.u[1] = af.u[2] = af.u[3] = 0u;
      }
      a[mt] = af.v;
    }
#pragma unroll
    for (int nt = 0; nt < 8; ++nt) {
      Frag bfr;
      bfr.q = *(const uint4*)&bsh[(((ks * 8 + nt) * 64) + lane) * 8];
      acc[0][nt] = __builtin_amdgcn_mfma_f32_16x16x32_bf16(a[0], bfr.v, acc[0][nt], 0, 0, 0);
      acc[1][nt] = __builtin_amdgcn_mfma_f32_16x16x32_bf16(a[1], bfr.v, acc[1][nt], 0, 0, 0);
    }
  }

  float b1v[8];
#pragma unroll
  for (int nt = 0; nt < 8; ++nt) b1v[nt] = fine ? 0.0f : b1[nt * 16 + ml];

#pragma unroll
  for (int mt = 0; mt < 2; ++mt) {
#pragma unroll
    for (int r = 0; r < 4; ++r) {
      const int row = rowStart + w * 32 + mt * 16 + qd * 4 + r;
      if (row < R) {
#pragma unroll
        for (int nt = 0; nt < 8; ++nt)
          P[row * 128 + nt * 16 + ml] = (u16)rne_bf16(acc[mt][nt][r] + b1v[nt]);
      }
    }
  }
}

// ---------------------------------------------------------------------------
// edge_kernel: 128 SORTED edges/block. W2 staged in LDS (32 KB), K-loop MFMA,
// same 32 KB reused as [128][128] bf16 contribution matrix; segment-sum via
// plain ds_read; global atomics only at block boundaries. hdk read as bf16 Hc.
// ---------------------------------------------------------------------------
__global__ __launch_bounds__(256, 4) void edge_kernel(
    const u16* __restrict__ Pf, const u16* __restrict__ Pc,
    const u16* __restrict__ BW2, const u16* __restrict__ Hc,
    const u32* __restrict__ spk, const float* __restrict__ b2,
    float* __restrict__ out) {
  __shared__ u16 smem[16384];  // 32 KB: W2 frags, then contrib[128][128] bf16
  __shared__ int sh_fi[128], sh_ci[128], sh_segstart[130];
  __shared__ int shS, shHead, shTail, shW0tot;

  const int tid = threadIdx.x;
  const int eb = blockIdx.x * 128;
  const int V = min(128, E_EDGES - eb);

  {  // stage W2 fragments (32 KB), coalesced
    uint4* d4 = (uint4*)smem;
    const uint4* s4 = (const uint4*)BW2;
#pragma unroll
    for (int k = 0; k < 8; ++k) d4[k * 256 + tid] = s4[k * 256 + tid];
  }
  if (tid < 128) {
    if (tid < V) {
      u32 p = spk[eb + tid];
      sh_fi[tid] = (int)(p >> 14);
      sh_ci[tid] = (int)(p & 16383u);
    } else { sh_fi[tid] = -1; sh_ci[tid] = 0; }
  }
  if (tid == 0) {
    shHead = (eb > 0) ? (int)(spk[eb - 1] >> 14) : -1;
    shTail = (eb + V < E_EDGES) ? (int)(spk[eb + V] >> 14) : -1;
  }
  __syncthreads();

  // segment scan over the 128 rows (waves 0-1)
  int f = 0, x = 0;
  if (tid < 128) {
    f = (tid < V) ? ((tid == 0) ? 1 : (sh_fi[tid] != sh_fi[tid - 1] ? 1 : 0)) : 0;
    x = f;
#pragma unroll
    for (int off = 1; off < 64; off <<= 1) {
      int y = __shfl_up(x, off, 64);
      if ((tid & 63) >= off) x += y;
    }
  }
  if (tid == 63) shW0tot = x;
  __syncthreads();
  if (tid >= 64 && tid < 128) x += shW0tot;
  if (tid < V) {
    if (f) sh_segstart[x - 1] = tid;
    if (tid == V - 1) { shS = x; sh_segstart[x] = V; }
  }
  __syncthreads();

  const int lane = tid & 63;
  const int w = tid >> 6;
  const int qd = lane >> 4;
  const int ml = lane & 15;

  int fiA[2], ciA[2]; bool vA[2];
#pragma unroll
  for (int mt = 0; mt < 2; ++mt) {
    const int lr = w * 32 + mt * 16 + ml;
    vA[mt] = lr < V;
    fiA[mt] = vA[mt] ? sh_fi[lr] : 0;
    ciA[mt] = vA[mt] ? sh_ci[lr] : 0;
  }

  f32x4 acc[2][8];
#pragma unroll
  for (int mt = 0; mt < 2; ++mt)
#pragma unroll
    for (int nt = 0; nt < 8; ++nt) acc[mt][nt] = (f32x4){0.f, 0.f, 0.f, 0.f};

  for (int ks = 0; ks < 4; ++ks) {
    const int k0 = ks * 32 + qd * 8;
    short8 a[2];
#pragma unroll
    for (int mt = 0; mt < 2; ++mt) {
      Frag af;
      if (vA[mt]) {
        uint4 pf = *(const uint4*)(Pf + fiA[mt] * 128 + k0);
        uint4 pc = *(const uint4*)(Pc + ciA[mt] * 128 + k0);
        af.u[0] = addrelu_pack(pf.x, pc.x);
        af.u[1] = addrelu_pack(pf.y, pc.y);
        af.u[2] = addrelu_pack(pf.z, pc.z);
        af.u[3] = addrelu_pack(pf.w, pc.w);
      } else {
        af.u[0] = af.u[1] = af.u[2] = af.u[3] = 0u;
      }
      a[mt] = af.v;
    }
#pragma unroll
    for (int nt = 0; nt < 8; ++nt) {
      Frag bfr;
      bfr.q = *(const uint4*)&smem[(((ks * 8 + nt) * 64) + lane) * 8];
      acc[0][nt] = __builtin_amdgcn_mfma_f32_16x16x32_bf16(a[0], bfr.v, acc[0][nt], 0, 0, 0);
      acc[1][nt] = __builtin_amdgcn_mfma_f32_16x16x32_bf16(a[1], bfr.v, acc[1][nt], 0, 0, 0);
    }
  }
  __syncthreads();  // all W2 LDS reads done; smem is now the contrib matrix

  float b2v[8];
#pragma unroll
  for (int nt = 0; nt < 8; ++nt) b2v[nt] = b2[nt * 16 + ml];

#pragma unroll
  for (int mt = 0; mt < 2; ++mt) {
#pragma unroll
    for (int r = 0; r < 4; ++r) {
      const int lr = w * 32 + mt * 16 + qd * 4 + r;
      if (lr < V) {
        const u16* __restrict__ hrow = Hc + sh_ci[lr] * 128;
#pragma unroll
        for (int nt = 0; nt < 8; ++nt) {
          const int col = nt * 16 + ml;
          const float psi = fmaxf(acc[mt][nt][r] + b2v[nt], 0.0f);
          smem[lr * 128 + col] = trunc_bf16(psi * up_bf(hrow[col]));
        }
      }
    }
  }
  __syncthreads();

  // segment reduce: thread owns (segment, col-pair); plain LDS reads, one
  // store (or boundary atomic) per output element.
  const int S = shS;
  for (int idx = tid; idx < S * 64; idx += 256) {
    const int s = idx >> 6, cp = idx & 63;
    const int r0 = sh_segstart[s], r1 = sh_segstart[s + 1];
    float a0 = 0.f, a1 = 0.f;
    for (int r = r0; r < r1; ++r) {
      const u32 v = *(const u32*)&smem[r * 128 + cp * 2];
      a0 += lo_bf(v);
      a1 += hi_bf(v);
    }
    const int fi = sh_fi[r0];
    float* op = out + (size_t)fi * 128 + cp * 2;
    const bool at = (s == 0 && shHead == fi) || (s == S - 1 && shTail == fi);
    if (at) { atomicAdd(op, a0); atomicAdd(op + 1, a1); }
    else { op[0] = a0; op[1] = a1; }
  }
}

extern "C" void kernel_launch(void* const* d_in, const int* in_sizes, int n_in,
                              void* d_out, int out_size, void* d_ws, size_t ws_size,
                              hipStream_t stream) {
  const float* h_dk = (const float*)d_in[0];
  const float* h_si = (const float*)d_in[1];
  const float* h_sk = (const float*)d_in[2];
  const float* h_di = (const float*)d_in[3];
  const int* fidx = (const int*)d_in[4];
  const int* cidx = (const int*)d_in[5];
  const float* W1 = (const float*)d_in[6];
  const float* b1 = (const float*)d_in[7];
  const float* W2 = (const float*)d_in[8];
  const float* b2 = (const float*)d_in[9];
  float* out = (float*)d_out;

  // workspace layout (~23.2 MiB)
  u16* Pf   = (u16*)d_ws;                      // 6,400,000 u16
  u16* Pc   = Pf + (size_t)NUM_FINE * 128;     // 1,600,000
  u16* BW1f = Pc + (size_t)NUM_COARSE * 128;   // 32768
  u16* BW1c = BW1f + 32768;                    // 32768
  u16* BW2  = BW1c + 32768;                    // 16384
  u16* Hc   = BW2 + 16384;                     // 1,600,000 (h_dk as bf16)
  u32* cnt4 = (u32*)(Hc + (size_t)NUM_COARSE * 128);  // 4*PADF u32 (counts->bases)
  u32* spk  = cnt4 + 4 * PADF;                 // 600,000 u32
  u8*  rk   = (u8*)(spk + E_EDGES);            // 600,000 u8

  hipMemsetAsync(cnt4, 0, 4 * PADF * sizeof(u32), stream);

  prep1<<<CONVERT_BLOCKS + HCONV_BLOCKS + COUNT_BLOCKS, 256, 0, stream>>>(
      W1, W2, BW1f, BW1c, BW2, h_dk, Hc, fidx, cnt4, rk);
  scan_kernel<<<1, 1024, 0, stream>>>(cnt4);
  prep2<<<SCATTER_BLOCKS + ZOUT_BLOCKS + FINE_BLOCKS + COARSE_BLOCKS, 256, 0, stream>>>(
      fidx, cidx, cnt4, rk, spk, out, h_dk, h_si, h_sk, h_di,
      BW1f, BW1c, b1, Pf, Pc);
  edge_kernel<<<(E_EDGES + 127) / 128, 256, 0, stream>>>(
      Pf, Pc, BW2, Hc, spk, b2, out);
}

// Round 6
// 239.682 us; speedup vs baseline: 1.4068x; 1.3874x over previous
//
#include <hip/hip_runtime.h>

typedef unsigned char u8;
typedef unsigned short u16;
typedef unsigned int u32;

#define E_EDGES 600000
#define NUM_FINE 50000
#define NUM_COARSE 12500
#define FINE_BLOCKS 391     // ceil(50000/128)
#define COARSE_BLOCKS 98    // ceil(12500/128)
#define CONVERT_BLOCKS 320
#define HCONV_BLOCKS 782    // ceil(1.6M/(256*8))
#define COUNT_BLOCKS 2344   // ceil(600000/256)
#define SCATTER_BLOCKS 2344
#define ZOUT_BLOCKS 625     // 625*256*10 float4 = 6.4M floats
#define PADF 53248          // padded per-copy counter length
#define SCAN_BLOCKS 196     // ceil(50000/256)

typedef __attribute__((ext_vector_type(8))) short short8;
typedef __attribute__((ext_vector_type(4))) float f32x4;

union Frag { short8 v; u16 s[8]; u32 u[4]; uint4 q; };

__device__ __forceinline__ u32 rne_bf16(float f) {
  union { float f; u32 u; } v; v.f = f;
  return (v.u + 0x7FFFu + ((v.u >> 16) & 1u)) >> 16;
}
__device__ __forceinline__ float hi_bf(u32 u) {
  union { u32 x; float f; } v; v.x = u & 0xFFFF0000u; return v.f;
}
__device__ __forceinline__ float lo_bf(u32 u) {
  union { u32 x; float f; } v; v.x = u << 16; return v.f;
}
__device__ __forceinline__ float up_bf(u16 u) {
  union { u32 x; float f; } v; v.x = ((u32)u) << 16; return v.f;
}
__device__ __forceinline__ u32 pack_trunc(float hi, float lo) {
  union { float f; u32 x; } a, b; a.f = hi; b.f = lo;
  return __builtin_amdgcn_perm(a.x, b.x, 0x07060302u);
}
__device__ __forceinline__ u32 addrelu_pack(u32 a, u32 b) {
  float lo = fmaxf(lo_bf(a) + lo_bf(b), 0.0f);
  float hi = fmaxf(hi_bf(a) + hi_bf(b), 0.0f);
  return pack_trunc(hi, lo);
}
__device__ __forceinline__ u16 trunc_bf16(float f) {
  union { float f; u32 u; } v; v.f = f;
  return (u16)(v.u >> 16);
}
__device__ __forceinline__ u32 rne_pack(float lo, float hi) {
  return rne_bf16(lo) | (rne_bf16(hi) << 16);
}

// ---------------------------------------------------------------------------
// prep1: [0,320) convert W1/W2 to fragment-ordered bf16;
//        [320,+782) convert h_dk -> bf16 Hc;
//        [+2344) count fidx into 4 privatized copies, record rank u8.
// ---------------------------------------------------------------------------
__global__ void prep1(const float* __restrict__ W1, const float* __restrict__ W2,
                      u16* __restrict__ BW1f, u16* __restrict__ BW1c,
                      u16* __restrict__ BW2,
                      const float* __restrict__ h_dk, u16* __restrict__ Hc,
                      const int* __restrict__ fidx, u32* __restrict__ cnt4,
                      u8* __restrict__ rk) {
  if (blockIdx.x < CONVERT_BLOCKS) {
    int o = blockIdx.x * 256 + threadIdx.x;
    if (o >= 81920) return;
    int which = (o < 32768) ? 0 : (o < 65536 ? 1 : 2);
    int idx = (which == 2) ? (o - 65536) : (o & 32767);
    int j = idx & 7, lane = (idx >> 3) & 63, nt = (idx >> 9) & 7, ks = idx >> 12;
    int k = ks * 32 + (lane >> 4) * 8 + j;
    int n = nt * 16 + (lane & 15);
    float v;
    if (which == 2) v = W2[k * 128 + n];
    else {
      int row;
      if (which == 0) row = (k < 128) ? k : (256 + (k - 128));          // si | di
      else            row = (k < 128) ? (128 + k) : (384 + (k - 128));  // sk | dk
      v = W1[row * 128 + n];
    }
    u16 b = (u16)rne_bf16(v);
    if (which == 0) BW1f[idx] = b; else if (which == 1) BW1c[idx] = b; else BW2[idx] = b;
  } else if (blockIdx.x < CONVERT_BLOCKS + HCONV_BLOCKS) {
    int t = (blockIdx.x - CONVERT_BLOCKS) * 256 + threadIdx.x;
    if (t < (NUM_COARSE * 128) / 8) {
      const float4* s = (const float4*)(h_dk + t * 8);
      float4 v0 = s[0], v1 = s[1];
      uint4 o;
      o.x = rne_pack(v0.x, v0.y);
      o.y = rne_pack(v0.z, v0.w);
      o.z = rne_pack(v1.x, v1.y);
      o.w = rne_pack(v1.z, v1.w);
      *(uint4*)(Hc + t * 8) = o;
    }
  } else {
    int e = (blockIdx.x - CONVERT_BLOCKS - HCONV_BLOCKS) * 256 + threadIdx.x;
    if (e < E_EDGES) {
      int fi = fidx[e];
      u32 r = atomicAdd(&cnt4[(e & 3) * PADF + fi], 1u);
      rk[e] = (u8)r;
    }
  }
}

// ---------------------------------------------------------------------------
// scan1: per-block (256 fi) total over 4 copies -> roots[b]
// ---------------------------------------------------------------------------
__global__ void scan1(const u32* __restrict__ cnt4, u32* __restrict__ roots) {
  __shared__ u32 wsum[4];
  const int tid = threadIdx.x, lane = tid & 63, w = tid >> 6;
  const int fi = blockIdx.x * 256 + tid;
  u32 tot = 0;
  if (fi < NUM_FINE)
    tot = cnt4[fi] + cnt4[PADF + fi] + cnt4[2 * PADF + fi] + cnt4[3 * PADF + fi];
  u32 x = tot;
#pragma unroll
  for (int off = 32; off >= 1; off >>= 1) x += __shfl_down(x, off, 64);
  if (lane == 0) wsum[w] = x;
  __syncthreads();
  if (tid == 0) roots[blockIdx.x] = wsum[0] + wsum[1] + wsum[2] + wsum[3];
}

// ---------------------------------------------------------------------------
// scan2: block base = sum(roots[j<b]); in-block exclusive scan of totals;
// write per-copy bases in-place into cnt4.
// ---------------------------------------------------------------------------
__global__ void scan2(u32* __restrict__ cnt4, const u32* __restrict__ roots) {
  __shared__ u32 wsum[4], wred[4];
  __shared__ u32 sh_bbase;
  const int tid = threadIdx.x, lane = tid & 63, w = tid >> 6;
  const int fi = blockIdx.x * 256 + tid;

  u32 c0 = 0, c1 = 0, c2 = 0, c3 = 0;
  if (fi < NUM_FINE) {
    c0 = cnt4[fi];            c1 = cnt4[PADF + fi];
    c2 = cnt4[2 * PADF + fi]; c3 = cnt4[3 * PADF + fi];
  }
  const u32 tot = c0 + c1 + c2 + c3;

  // block base: sum of roots[j] for j < blockIdx.x (SCAN_BLOCKS <= 256)
  u32 rv = (tid < (int)blockIdx.x && tid < SCAN_BLOCKS) ? roots[tid] : 0;
#pragma unroll
  for (int off = 32; off >= 1; off >>= 1) rv += __shfl_down(rv, off, 64);
  if (lane == 0) wred[w] = rv;
  __syncthreads();
  if (tid == 0) sh_bbase = wred[0] + wred[1] + wred[2] + wred[3];

  // in-block inclusive scan of tot
  u32 xi = tot;
#pragma unroll
  for (int off = 1; off < 64; off <<= 1) {
    u32 y = __shfl_up(xi, off, 64);
    if (lane >= off) xi += y;
  }
  if (lane == 63) wsum[w] = xi;
  __syncthreads();
  u32 woffs = 0;
  for (int k = 0; k < w; ++k) woffs += wsum[k];
  const u32 g = sh_bbase + woffs + xi - tot;  // global exclusive base of fi

  if (fi < NUM_FINE) {
    cnt4[fi] = g;
    cnt4[PADF + fi] = g + c0;
    cnt4[2 * PADF + fi] = g + c0 + c1;
    cnt4[3 * PADF + fi] = g + c0 + c1 + c2;
  }
}

// ---------------------------------------------------------------------------
// prep2: [0,2344) atomic-free scatter; [+625) zero-fill out; [+489) precompute.
// ---------------------------------------------------------------------------
__global__ __launch_bounds__(256, 2) void prep2(
    const int* __restrict__ fidx, const int* __restrict__ cidx,
    const u32* __restrict__ base4, const u8* __restrict__ rk,
    u32* __restrict__ spk, float* __restrict__ out,
    const float* __restrict__ h_dk, const float* __restrict__ h_si,
    const float* __restrict__ h_sk, const float* __restrict__ h_di,
    const u16* __restrict__ BW1f, const u16* __restrict__ BW1c,
    const float* __restrict__ b1, u16* __restrict__ Pf, u16* __restrict__ Pc) {
  __shared__ u16 bsh[32768];  // 64 KB (W1-slice fragments)

  if (blockIdx.x < SCATTER_BLOCKS) {
    int e = blockIdx.x * 256 + threadIdx.x;
    if (e < E_EDGES) {
      int fi = fidx[e];
      u32 pos = base4[(e & 3) * PADF + fi] + rk[e];
      spk[pos] = ((u32)fi << 14) | (u32)cidx[e];  // fi<2^16, ci<2^14
    }
    return;
  }
  if (blockIdx.x < SCATTER_BLOCKS + ZOUT_BLOCKS) {
    const int zb = blockIdx.x - SCATTER_BLOCKS;
    float4* o4 = (float4*)out;
    const float4 z = {0.f, 0.f, 0.f, 0.f};
    int idx = zb * 2560 + threadIdx.x;
#pragma unroll
    for (int i = 0; i < 10; ++i) o4[idx + i * 256] = z;
    return;
  }

  const int b = blockIdx.x - SCATTER_BLOCKS - ZOUT_BLOCKS;
  const bool fine = b < FINE_BLOCKS;
  const int rowStart = fine ? b * 128 : (b - FINE_BLOCKS) * 128;
  const int R = fine ? NUM_FINE : NUM_COARSE;
  const float* __restrict__ X1 = fine ? h_si : h_sk;
  const float* __restrict__ X2 = fine ? h_di : h_dk;
  const u16* __restrict__ BW = fine ? BW1f : BW1c;
  u16* __restrict__ P = fine ? Pf : Pc;

  const int tid = threadIdx.x;
  {  // stage 64 KB of B fragments, coalesced
    uint4* d4 = (uint4*)bsh;
    const uint4* s4 = (const uint4*)BW;
#pragma unroll
    for (int k = 0; k < 16; ++k) d4[k * 256 + tid] = s4[k * 256 + tid];
  }
  __syncthreads();

  const int lane = tid & 63;
  const int w = tid >> 6;
  const int qd = lane >> 4;
  const int ml = lane & 15;

  int rowA[2]; bool vA[2];
#pragma unroll
  for (int mt = 0; mt < 2; ++mt) {
    rowA[mt] = rowStart + w * 32 + mt * 16 + ml;
    vA[mt] = rowA[mt] < R;
  }

  f32x4 acc[2][8];
#pragma unroll
  for (int mt = 0; mt < 2; ++mt)
#pragma unroll
    for (int nt = 0; nt < 8; ++nt) acc[mt][nt] = (f32x4){0.f, 0.f, 0.f, 0.f};

  for (int ks = 0; ks < 8; ++ks) {
    const int k0 = ks * 32 + qd * 8;  // 0..255
    short8 a[2];
#pragma unroll
    for (int mt = 0; mt < 2; ++mt) {
      Frag af;
      if (vA[mt]) {
        const float* src = (k0 < 128) ? (X1 + rowA[mt] * 128 + k0)
                                      : (X2 + rowA[mt] * 128 + (k0 - 128));
        const float4* s4 = (const float4*)src;
        float4 v0 = s4[0], v1 = s4[1];
        af.u[0] = pack_trunc(v0.y, v0.x);
        af.u[1] = pack_trunc(v0.w, v0.z);
        af.u[2] = pack_trunc(v1.y, v1.x);
        af.u[3] = pack_trunc(v1.w, v1.z);
      } else {
        af.u[0] = af.u[1] = af.u[2] = af.u[3] = 0u;
      }
      a[mt] = af.v;
    }
#pragma unroll
    for (int nt = 0; nt < 8; ++nt) {
      Frag bfr;
      bfr.q = *(const uint4*)&bsh[(((ks * 8 + nt) * 64) + lane) * 8];
      acc[0][nt] = __builtin_amdgcn_mfma_f32_16x16x32_bf16(a[0], bfr.v, acc[0][nt], 0, 0, 0);
      acc[1][nt] = __builtin_amdgcn_mfma_f32_16x16x32_bf16(a[1], bfr.v, acc[1][nt], 0, 0, 0);
    }
  }

  float b1v[8];
#pragma unroll
  for (int nt = 0; nt < 8; ++nt) b1v[nt] = fine ? 0.0f : b1[nt * 16 + ml];

#pragma unroll
  for (int mt = 0; mt < 2; ++mt) {
#pragma unroll
    for (int r = 0; r < 4; ++r) {
      const int row = rowStart + w * 32 + mt * 16 + qd * 4 + r;
      if (row < R) {
#pragma unroll
        for (int nt = 0; nt < 8; ++nt)
          P[row * 128 + nt * 16 + ml] = (u16)rne_bf16(acc[mt][nt][r] + b1v[nt]);
      }
    }
  }
}

// ---------------------------------------------------------------------------
// edge_kernel: 128 SORTED edges/block. W2 staged in LDS (32 KB), K-loop MFMA,
// same 32 KB reused as [128][128] bf16 contribution matrix; segment-sum via
// plain ds_read; global atomics only at block boundaries. hdk read as bf16 Hc.
// ---------------------------------------------------------------------------
__global__ __launch_bounds__(256, 4) void edge_kernel(
    const u16* __restrict__ Pf, const u16* __restrict__ Pc,
    const u16* __restrict__ BW2, const u16* __restrict__ Hc,
    const u32* __restrict__ spk, const float* __restrict__ b2,
    float* __restrict__ out) {
  __shared__ u16 smem[16384];  // 32 KB: W2 frags, then contrib[128][128] bf16
  __shared__ int sh_fi[128], sh_ci[128], sh_segstart[130];
  __shared__ int shS, shHead, shTail, shW0tot;

  const int tid = threadIdx.x;
  const int eb = blockIdx.x * 128;
  const int V = min(128, E_EDGES - eb);

  {  // stage W2 fragments (32 KB), coalesced
    uint4* d4 = (uint4*)smem;
    const uint4* s4 = (const uint4*)BW2;
#pragma unroll
    for (int k = 0; k < 8; ++k) d4[k * 256 + tid] = s4[k * 256 + tid];
  }
  if (tid < 128) {
    if (tid < V) {
      u32 p = spk[eb + tid];
      sh_fi[tid] = (int)(p >> 14);
      sh_ci[tid] = (int)(p & 16383u);
    } else { sh_fi[tid] = -1; sh_ci[tid] = 0; }
  }
  if (tid == 0) {
    shHead = (eb > 0) ? (int)(spk[eb - 1] >> 14) : -1;
    shTail = (eb + V < E_EDGES) ? (int)(spk[eb + V] >> 14) : -1;
  }
  __syncthreads();

  // segment scan over the 128 rows (waves 0-1)
  int f = 0, x = 0;
  if (tid < 128) {
    f = (tid < V) ? ((tid == 0) ? 1 : (sh_fi[tid] != sh_fi[tid - 1] ? 1 : 0)) : 0;
    x = f;
#pragma unroll
    for (int off = 1; off < 64; off <<= 1) {
      int y = __shfl_up(x, off, 64);
      if ((tid & 63) >= off) x += y;
    }
  }
  if (tid == 63) shW0tot = x;
  __syncthreads();
  if (tid >= 64 && tid < 128) x += shW0tot;
  if (tid < V) {
    if (f) sh_segstart[x - 1] = tid;
    if (tid == V - 1) { shS = x; sh_segstart[x] = V; }
  }
  __syncthreads();

  const int lane = tid & 63;
  const int w = tid >> 6;
  const int qd = lane >> 4;
  const int ml = lane & 15;

  int fiA[2], ciA[2]; bool vA[2];
#pragma unroll
  for (int mt = 0; mt < 2; ++mt) {
    const int lr = w * 32 + mt * 16 + ml;
    vA[mt] = lr < V;
    fiA[mt] = vA[mt] ? sh_fi[lr] : 0;
    ciA[mt] = vA[mt] ? sh_ci[lr] : 0;
  }

  f32x4 acc[2][8];
#pragma unroll
  for (int mt = 0; mt < 2; ++mt)
#pragma unroll
    for (int nt = 0; nt < 8; ++nt) acc[mt][nt] = (f32x4){0.f, 0.f, 0.f, 0.f};

  for (int ks = 0; ks < 4; ++ks) {
    const int k0 = ks * 32 + qd * 8;
    short8 a[2];
#pragma unroll
    for (int mt = 0; mt < 2; ++mt) {
      Frag af;
      if (vA[mt]) {
        uint4 pf = *(const uint4*)(Pf + fiA[mt] * 128 + k0);
        uint4 pc = *(const uint4*)(Pc + ciA[mt] * 128 + k0);
        af.u[0] = addrelu_pack(pf.x, pc.x);
        af.u[1] = addrelu_pack(pf.y, pc.y);
        af.u[2] = addrelu_pack(pf.z, pc.z);
        af.u[3] = addrelu_pack(pf.w, pc.w);
      } else {
        af.u[0] = af.u[1] = af.u[2] = af.u[3] = 0u;
      }
      a[mt] = af.v;
    }
#pragma unroll
    for (int nt = 0; nt < 8; ++nt) {
      Frag bfr;
      bfr.q = *(const uint4*)&smem[(((ks * 8 + nt) * 64) + lane) * 8];
      acc[0][nt] = __builtin_amdgcn_mfma_f32_16x16x32_bf16(a[0], bfr.v, acc[0][nt], 0, 0, 0);
      acc[1][nt] = __builtin_amdgcn_mfma_f32_16x16x32_bf16(a[1], bfr.v, acc[1][nt], 0, 0, 0);
    }
  }
  __syncthreads();  // all W2 LDS reads done; smem is now the contrib matrix

  float b2v[8];
#pragma unroll
  for (int nt = 0; nt < 8; ++nt) b2v[nt] = b2[nt * 16 + ml];

#pragma unroll
  for (int mt = 0; mt < 2; ++mt) {
#pragma unroll
    for (int r = 0; r < 4; ++r) {
      const int lr = w * 32 + mt * 16 + qd * 4 + r;
      if (lr < V) {
        const u16* __restrict__ hrow = Hc + sh_ci[lr] * 128;
#pragma unroll
        for (int nt = 0; nt < 8; ++nt) {
          const int col = nt * 16 + ml;
          const float psi = fmaxf(acc[mt][nt][r] + b2v[nt], 0.0f);
          smem[lr * 128 + col] = trunc_bf16(psi * up_bf(hrow[col]));
        }
      }
    }
  }
  __syncthreads();

  // segment reduce: thread owns (segment, col-pair); plain LDS reads, one
  // store (or boundary atomic) per output element.
  const int S = shS;
  for (int idx = tid; idx < S * 64; idx += 256) {
    const int s = idx >> 6, cp = idx & 63;
    const int r0 = sh_segstart[s], r1 = sh_segstart[s + 1];
    float a0 = 0.f, a1 = 0.f;
    for (int r = r0; r < r1; ++r) {
      const u32 v = *(const u32*)&smem[r * 128 + cp * 2];
      a0 += lo_bf(v);
      a1 += hi_bf(v);
    }
    const int fi = sh_fi[r0];
    float* op = out + (size_t)fi * 128 + cp * 2;
    const bool at = (s == 0 && shHead == fi) || (s == S - 1 && shTail == fi);
    if (at) { atomicAdd(op, a0); atomicAdd(op + 1, a1); }
    else { op[0] = a0; op[1] = a1; }
  }
}

extern "C" void kernel_launch(void* const* d_in, const int* in_sizes, int n_in,
                              void* d_out, int out_size, void* d_ws, size_t ws_size,
                              hipStream_t stream) {
  const float* h_dk = (const float*)d_in[0];
  const float* h_si = (const float*)d_in[1];
  const float* h_sk = (const float*)d_in[2];
  const float* h_di = (const float*)d_in[3];
  const int* fidx = (const int*)d_in[4];
  const int* cidx = (const int*)d_in[5];
  const float* W1 = (const float*)d_in[6];
  const float* b1 = (const float*)d_in[7];
  const float* W2 = (const float*)d_in[8];
  const float* b2 = (const float*)d_in[9];
  float* out = (float*)d_out;

  // workspace layout (~23.2 MiB)
  u16* Pf   = (u16*)d_ws;                      // 6,400,000 u16
  u16* Pc   = Pf + (size_t)NUM_FINE * 128;     // 1,600,000
  u16* BW1f = Pc + (size_t)NUM_COARSE * 128;   // 32768
  u16* BW1c = BW1f + 32768;                    // 32768
  u16* BW2  = BW1c + 32768;                    // 16384
  u16* Hc   = BW2 + 16384;                     // 1,600,000 (h_dk as bf16)
  u32* cnt4 = (u32*)(Hc + (size_t)NUM_COARSE * 128);  // 4*PADF u32 (counts->bases)
  u32* spk  = cnt4 + 4 * PADF;                 // 600,000 u32
  u8*  rk   = (u8*)(spk + E_EDGES);            // 600,000 u8
  u32* roots = (u32*)(rk + E_EDGES);           // 196 u32

  hipMemsetAsync(cnt4, 0, 4 * PADF * sizeof(u32), stream);

  prep1<<<CONVERT_BLOCKS + HCONV_BLOCKS + COUNT_BLOCKS, 256, 0, stream>>>(
      W1, W2, BW1f, BW1c, BW2, h_dk, Hc, fidx, cnt4, rk);
  scan1<<<SCAN_BLOCKS, 256, 0, stream>>>(cnt4, roots);
  scan2<<<SCAN_BLOCKS, 256, 0, stream>>>(cnt4, roots);
  prep2<<<SCATTER_BLOCKS + ZOUT_BLOCKS + FINE_BLOCKS + COARSE_BLOCKS, 256, 0, stream>>>(
      fidx, cidx, cnt4, rk, spk, out, h_dk, h_si, h_sk, h_di,
      BW1f, BW1c, b1, Pf, Pc);
  edge_kernel<<<(E_EDGES + 127) / 128, 256, 0, stream>>>(
      Pf, Pc, BW2, Hc, spk, b2, out);
}